// Round 5
// baseline (775.981 us; speedup 1.0000x reference)
//
#include <hip/hip_runtime.h>

#define BB 64
#define TT 1024
#define CC 256

typedef short v8s __attribute__((ext_vector_type(8)));
typedef float v4f __attribute__((ext_vector_type(4)));

#define REP8(X) X(0) X(1) X(2) X(3) X(4) X(5) X(6) X(7)

// fp32 -> bf16 round-to-nearest-even (finite inputs)
static __device__ __forceinline__ short f2bf(float f) {
  unsigned u = __float_as_uint(f);
  return (short)((u + 0x7FFFu + ((u >> 16) & 1u)) >> 16);
}

// LDS-only barrier: lgkmcnt(0) + s_barrier, NO vmcnt drain (vs __syncthreads
// which drains vmcnt(0) and puts global load/store latency on the step path).
static __device__ __forceinline__ void fast_barrier() {
  asm volatile("s_waitcnt lgkmcnt(0)\n\ts_barrier" ::: "memory");
}

// One block (512 thr = 8 waves) per batch chain; ONE barrier per step.
// p-domain recurrence: P_t = E_t (.) (W^T P_{t-1}) / sigma_t, with
//   E_t = exp(e_t)            precomputed off-path from distance-2 prefetch
//   sigma_t = P_{t-1}[0]      lag-1 LDS broadcast (s_scale, 2-deep)
//   C_t = C_{t-1} + log(sigma_t)  uniform register; alpha_t = log(P_t) + C_t
// Every lane of wave w holds r for cols {w*32+nl, +16} straight from its MFMA
// accumulators (D rows replicated by A-broadcast) — no s_r round-trip.
// alpha outputs (log + store) are deferred one step into the MFMA shadow.
// W = exp(trans) register-resident as 16 named bf16 B-fragments per wave.
// Range: P in [e^-34, e^25] worst case; r <= ~4e29 — fp32/bf16 safe.
__global__ __launch_bounds__(512, 2)
void crf_fwd(const float* __restrict__ emis,      // [B,T,C]
             const float* __restrict__ trans,     // [B,C,C]
             const int* __restrict__ seq_lens,    // [B]
             float* __restrict__ out_alpha,       // [B,T,C]
             float* __restrict__ out_logz)        // [B]
{
  const int b = blockIdx.x;
  const int tid = threadIdx.x;
  const int lane = tid & 63;
  const int wv = tid >> 6;        // wave 0..7 -> cols [32*wv, 32*wv+32)
  const int quad = lane >> 4;     // 0..3
  const int nl = lane & 15;
  const int k0q = quad * 8;
  const int col0 = wv * 32 + nl;
  const int col1 = col0 + 16;

  __shared__ unsigned short __align__(16) s_pbf[2][CC];  // P (bf16), dbuf
  __shared__ float __align__(16) s_last[CC];             // alpha at L-1
  __shared__ float s_scale[2];                           // sigma broadcast

  const float* eb = emis + (size_t)b * TT * CC;
  float* ab = out_alpha + (size_t)b * TT * CC;
  const int L = seq_lens[b];

  // ---- L3 pre-warm: stream this block's 1 MB emission slab once ----
  {
    const float4* e4 = (const float4*)eb;
    float acc = 0.f;
    #pragma unroll 4
    for (int i = tid; i < TT * CC / 4; i += 512) {
      float4 v = e4[i];
      acc += (v.x + v.y) + (v.z + v.w);
    }
    if (acc == 1.25e38f) s_scale[1] = acc;   // never true; defeats DCE
  }

  // ---- one-time: W = exp(trans) into 16 named B-fragments per wave ----
  const float* tb = trans + (size_t)b * CC * CC;
  const int n0 = col0;            // column for tile0; tile1 = n0 + 16
#define DECLB(q) v8s B0_##q, B1_##q;
  REP8(DECLB)
#define INITB(q) { \
  const float* pp = tb + (size_t)(q * 32 + k0q) * CC + n0; \
  B0_##q = (v8s){ f2bf(__expf(pp[0*CC])), f2bf(__expf(pp[1*CC])), \
                  f2bf(__expf(pp[2*CC])), f2bf(__expf(pp[3*CC])), \
                  f2bf(__expf(pp[4*CC])), f2bf(__expf(pp[5*CC])), \
                  f2bf(__expf(pp[6*CC])), f2bf(__expf(pp[7*CC])) }; \
  const float* qq = pp + 16; \
  B1_##q = (v8s){ f2bf(__expf(qq[0*CC])), f2bf(__expf(qq[1*CC])), \
                  f2bf(__expf(qq[2*CC])), f2bf(__expf(qq[3*CC])), \
                  f2bf(__expf(qq[4*CC])), f2bf(__expf(qq[5*CC])), \
                  f2bf(__expf(qq[6*CC])), f2bf(__expf(qq[7*CC])) }; }
  REP8(INITB)

  // ---- prologue: t = 0 ----
  float a00 = eb[0];                         // broadcast
  float g0 = eb[col0], g1 = eb[col1];        // e[0] = alpha_0
  if (quad == 2) ab[col0] = g0;
  if (quad == 3) ab[col1] = g1;
  if (L == 1 && quad < 2) s_last[wv * 32 + quad * 16 + nl] = quad ? g1 : g0;
  if (quad < 2)
    s_pbf[0][wv * 32 + quad * 16 + nl] =
        (unsigned short)f2bf(__expf((quad ? g1 : g0) - a00));
  if (tid == 0) s_scale[0] = 1.0f;           // P_0[0] = exp(a00 - a00)
  float C = a00;                             // C_0
  float t0 = eb[CC + col0], t1 = eb[CC + col1];       // e[1]
  float E0 = __expf(t0), E1 = __expf(t1);             // E for step 1
  float f0 = eb[2 * CC + col0], f1 = eb[2 * CC + col1];  // e[2] in flight
  float pv0 = 1.f, pv1 = 1.f;                // v(t-1) for deferred stores
  __syncthreads();

  // ---- main chain: ONE fast_barrier per step ----
  for (int t = 1; t < TT; ++t) {
    // issue e[t+2] prefetch (2-step budget; no vmcnt drain at barriers)
    int tp2 = (t + 2 < TT) ? t + 2 : TT - 1;
    float fn0 = eb[(size_t)tp2 * CC + col0];
    float fn1 = eb[(size_t)tp2 * CC + col1];

    float sig = s_scale[(t - 1) & 1];        // lag-1 broadcast

    // deferred alpha store for row t-1 (off-path, in MFMA shadow)
    if (t >= 2) {
      if (quad == 2) ab[(size_t)(t - 1) * CC + col0] = __logf(pv0) + C;
      if (quad == 3) ab[(size_t)(t - 1) * CC + col1] = __logf(pv1) + C;
    }
    float inv = 1.0f / sig;                  // off-path
    C += __logf(sig);                        // C_t (uniform)

    // r = W^T P_{t-1}: 16 MFMAs, 4 independent chains of 4
    const unsigned short* pbR = s_pbf[(t - 1) & 1];
    v4f c0a = {0,0,0,0}, c0b = {0,0,0,0}, c1a = {0,0,0,0}, c1b = {0,0,0,0};
#define MFA(q) { v8s a_ = *(const v8s*)(const void*)(pbR + q * 32 + k0q); \
    c0a = __builtin_amdgcn_mfma_f32_16x16x32_bf16(a_, B0_##q, c0a, 0, 0, 0); \
    c1a = __builtin_amdgcn_mfma_f32_16x16x32_bf16(a_, B1_##q, c1a, 0, 0, 0); }
#define MFB(q) { v8s a_ = *(const v8s*)(const void*)(pbR + q * 32 + k0q); \
    c0b = __builtin_amdgcn_mfma_f32_16x16x32_bf16(a_, B0_##q, c0b, 0, 0, 0); \
    c1b = __builtin_amdgcn_mfma_f32_16x16x32_bf16(a_, B1_##q, c1b, 0, 0, 0); }
    MFA(0) MFB(4) MFA(1) MFB(5) MFA(2) MFB(6) MFA(3) MFB(7)

    // every lane holds r for its 2 cols (rows replicated)
    float r0 = c0a[0] + c0b[0];
    float r1 = c1a[0] + c1b[0];
    float v0 = (E0 * r0) * inv;              // P_t[col0] (fp32)
    float v1 = (E1 * r1) * inv;              // P_t[col1]

    if (quad < 2)
      s_pbf[t & 1][wv * 32 + quad * 16 + nl] =
          (unsigned short)f2bf(quad ? v1 : v0);
    if (wv == 0 && lane == 0) s_scale[t & 1] = v0;  // sigma_{t+1} = P_t[0]

    if (t == L - 1) {                        // rare, wave-uniform branch
      if (quad == 0) s_last[col0] = __logf(v0) + C;
      if (quad == 1) s_last[col1] = __logf(v1) + C;
    }

    E0 = __expf(f0); E1 = __expf(f1);        // E for t+1 (e[t+1] arrived)
    f0 = fn0; f1 = fn1;
    pv0 = v0; pv1 = v1;
    fast_barrier();
  }

  // ---- epilogue: store row TT-1, then log_Z ----
  if (quad == 2) ab[(size_t)(TT - 1) * CC + col0] = __logf(pv0) + C;
  if (quad == 3) ab[(size_t)(TT - 1) * CC + col1] = __logf(pv1) + C;
  __syncthreads();

  if (tid < 64) {
    float4 v = ((const float4*)s_last)[lane];
    float m = fmaxf(fmaxf(v.x, v.y), fmaxf(v.z, v.w));
    #pragma unroll
    for (int off = 32; off >= 1; off >>= 1)
      m = fmaxf(m, __shfl_xor(m, off, 64));
    float s = __expf(v.x - m) + __expf(v.y - m) + __expf(v.z - m) + __expf(v.w - m);
    #pragma unroll
    for (int off = 32; off >= 1; off >>= 1)
      s += __shfl_xor(s, off, 64);
    if (lane == 0) out_logz[b] = m + __logf(s);
  }
}

extern "C" void kernel_launch(void* const* d_in, const int* in_sizes, int n_in,
                              void* d_out, int out_size, void* d_ws, size_t ws_size,
                              hipStream_t stream) {
  const float* emis = (const float*)d_in[0];
  const float* trans = (const float*)d_in[1];
  const int* seq_lens = (const int*)d_in[2];
  float* out_alpha = (float*)d_out;
  float* out_logz = out_alpha + (size_t)BB * TT * CC;
  hipLaunchKernelGGL(crf_fwd, dim3(BB), dim3(512), 0, stream,
                     emis, trans, seq_lens, out_alpha, out_logz);
}

// Round 6
// 562.845 us; speedup vs baseline: 1.3787x; 1.3787x over previous
//
#include <hip/hip_runtime.h>

#define BB 64
#define TT 1024
#define CC 256

typedef short v8s __attribute__((ext_vector_type(8)));
typedef float v4f __attribute__((ext_vector_type(4)));

#define REP8(X) X(0) X(1) X(2) X(3) X(4) X(5) X(6) X(7)

// fp32 -> bf16 round-to-nearest-even (finite inputs)
static __device__ __forceinline__ short f2bf(float f) {
  unsigned u = __float_as_uint(f);
  return (short)((u + 0x7FFFu + ((u >> 16) & 1u)) >> 16);
}

// LDS-only barrier: lgkmcnt(0) + s_barrier, no vmcnt drain.
static __device__ __forceinline__ void fast_barrier() {
  asm volatile("s_waitcnt lgkmcnt(0)\n\ts_barrier" ::: "memory");
}

// 768 thr = 12 waves per block, one block per batch chain, 1 barrier/step.
// Waves 0-7 : MFMA-only. Wave w owns cols {w*32+nl, +16}; W = exp(trans)
//             register-resident as 16 named bf16 B-fragments (proven alloc).
//             Step: ds_read A(P_{t-1}) -> 16 MFMA -> v=(E*r)*inv -> bf16
//             ds_write. No transcendentals, no global memory on this path.
// Waves 8-11: helpers, lane j = tid-512. Prefetch e (distance 2, unroll-2
//             alternating regs -> no rotation copies -> no forced vmcnt),
//             stage E_{t+1}=exp(e_{t+1}) one step ahead (s_E dbuf), compute
//             deferred alpha_{t-1} = log(P bf16) + C and store, track
//             C += log(sigma), s_last.
// Recurrence (exp domain): P_t = E_t (.) (W^T P_{t-1}) / sigma_t,
//   sigma_t = P_{t-1}[0] (fp32 via s_scale), C_t = C_{t-1} + log sigma_t,
//   alpha_t = log P_t + C_t.  Range: P in [e^-34, e^25] worst case — safe.
__global__ __launch_bounds__(768, 3)
void crf_fwd(const float* __restrict__ emis,      // [B,T,C]
             const float* __restrict__ trans,     // [B,C,C]
             const int* __restrict__ seq_lens,    // [B]
             float* __restrict__ out_alpha,       // [B,T,C]
             float* __restrict__ out_logz)        // [B]
{
  const int b = blockIdx.x;
  const int tid = threadIdx.x;
  const int lane = tid & 63;
  const int wv = tid >> 6;        // 0..7 MFMA, 8..11 helper
  const int quad = lane >> 4;
  const int nl = lane & 15;
  const int k0q = quad * 8;
  const int col0 = (wv & 7) * 32 + nl;
  const int col1 = col0 + 16;
  const int j = tid - 512;        // helper column (negative for MFMA waves)

  __shared__ unsigned short __align__(16) s_pbf[2][CC];  // P (bf16), dbuf
  __shared__ float s_E[2][CC];                           // staged exp(e_t)
  __shared__ float __align__(16) s_last[CC];             // alpha at L-1
  __shared__ float s_scale[2];                           // sigma (fp32)

  const float* eb = emis + (size_t)b * TT * CC;
  float* ab = out_alpha + (size_t)b * TT * CC;
  const int L = seq_lens[b];

  // ---- L3 pre-warm: stream this block's 1 MB emission slab once ----
  {
    const float4* e4 = (const float4*)eb;
    float acc = 0.f;
    #pragma unroll 4
    for (int i = tid; i < TT * CC / 4; i += 768) {
      float4 v = e4[i];
      acc += (v.x + v.y) + (v.z + v.w);
    }
    if (acc == 1.25e38f) s_scale[1] = acc;   // never true; defeats DCE
  }

  // ---- B fragments (declared for all; initialized/used only by wv<8) ----
#define DECLB(q) v8s B0_##q, B1_##q;
  REP8(DECLB)

  float C = 0.f, LA = 0.f, LB = 0.f;   // helper state

  if (wv < 8) {
    const float* tb = trans + (size_t)b * CC * CC;
    const int n0 = col0;
#define INITB(q) { \
    const float* pp = tb + (size_t)(q * 32 + k0q) * CC + n0; \
    B0_##q = (v8s){ f2bf(__expf(pp[0*CC])), f2bf(__expf(pp[1*CC])), \
                    f2bf(__expf(pp[2*CC])), f2bf(__expf(pp[3*CC])), \
                    f2bf(__expf(pp[4*CC])), f2bf(__expf(pp[5*CC])), \
                    f2bf(__expf(pp[6*CC])), f2bf(__expf(pp[7*CC])) }; \
    const float* qq = pp + 16; \
    B1_##q = (v8s){ f2bf(__expf(qq[0*CC])), f2bf(__expf(qq[1*CC])), \
                    f2bf(__expf(qq[2*CC])), f2bf(__expf(qq[3*CC])), \
                    f2bf(__expf(qq[4*CC])), f2bf(__expf(qq[5*CC])), \
                    f2bf(__expf(qq[6*CC])), f2bf(__expf(qq[7*CC])) }; }
    REP8(INITB)
  } else {
    // ---- helper prologue: t = 0 state ----
    float e0j = eb[j];
    float a00 = eb[0];
    ab[j] = e0j;                                   // alpha_0 exact
    C = a00;                                       // C_0
    s_pbf[0][j] = (unsigned short)f2bf(__expf(e0j - a00));
    if (L == 1) s_last[j] = e0j;
    s_E[1][j] = __expf(eb[CC + j]);                // E_1 for step t=1
    LB = eb[2 * CC + j];                           // e[2] in flight
    if (tid == 512) s_scale[0] = 1.0f;             // sigma_1 = P_0[0]
  }
  __syncthreads();

  // ---- step macros ----
#define MFA(q) { v8s a_ = *(const v8s*)(const void*)(pbR + q * 32 + k0q); \
    c0a = __builtin_amdgcn_mfma_f32_16x16x32_bf16(a_, B0_##q, c0a, 0, 0, 0); \
    c1a = __builtin_amdgcn_mfma_f32_16x16x32_bf16(a_, B1_##q, c1a, 0, 0, 0); }
#define MFB(q) { v8s a_ = *(const v8s*)(const void*)(pbR + q * 32 + k0q); \
    c0b = __builtin_amdgcn_mfma_f32_16x16x32_bf16(a_, B0_##q, c0b, 0, 0, 0); \
    c1b = __builtin_amdgcn_mfma_f32_16x16x32_bf16(a_, B1_##q, c1b, 0, 0, 0); }

#define MSTEP(T, RB, WB) { \
    float sig = s_scale[RB]; \
    float E0 = s_E[WB][col0]; \
    float E1 = s_E[WB][col1]; \
    const unsigned short* pbR = s_pbf[RB]; \
    v4f c0a = {0,0,0,0}, c0b = {0,0,0,0}, c1a = {0,0,0,0}, c1b = {0,0,0,0}; \
    MFA(0) MFB(4) MFA(1) MFB(5) MFA(2) MFB(6) MFA(3) MFB(7) \
    float inv = 1.0f / sig; \
    float r0 = c0a[0] + c0b[0]; \
    float r1 = c1a[0] + c1b[0]; \
    float v0 = (E0 * r0) * inv; \
    float v1 = (E1 * r1) * inv; \
    if (quad < 2) \
      s_pbf[WB][col0 + quad * 16] = (unsigned short)f2bf(quad ? v1 : v0); \
    if (wv == 0 && lane == 0) s_scale[WB] = v0; \
  }

  // helper: at step T stage E_{T+1} into s_E[(T+1)&1] == s_E[RB]
#define HSTEP(T, RB, WB, LDREG, USEREG) { \
    int tp2 = (T) + 2; if (tp2 > TT - 1) tp2 = TT - 1; \
    LDREG = eb[(size_t)tp2 * CC + j]; \
    float sig = s_scale[RB]; \
    float P = __uint_as_float(((unsigned)s_pbf[RB][j]) << 16); \
    float a_prev = __logf(P) + C; \
    if ((T) >= 2) ab[(size_t)((T) - 1) * CC + j] = a_prev; \
    if ((T) == L) s_last[j] = a_prev; \
    C += __logf(sig); \
    if ((T) < TT - 1) s_E[RB][j] = __expf(USEREG); \
  }

  // ---- main chain: unroll-2, one fast_barrier per step ----
  for (int t = 1; t + 1 < TT; t += 2) {
    if (wv < 8) { MSTEP(t, 0, 1) } else { HSTEP(t, 0, 1, LA, LB) }
    fast_barrier();
    if (wv < 8) { MSTEP(t + 1, 1, 0) } else { HSTEP(t + 1, 1, 0, LB, LA) }
    fast_barrier();
  }
  // tail step t = TT-1 (odd): RB=0, WB=1
  if (wv < 8) { MSTEP(TT - 1, 0, 1) } else { HSTEP(TT - 1, 0, 1, LA, LB) }
  fast_barrier();

  // ---- epilogue: alpha_{TT-1} by helpers, then log_Z ----
  if (wv >= 8) {
    float P = __uint_as_float(((unsigned)s_pbf[(TT - 1) & 1][j]) << 16);
    float a_last = __logf(P) + C;                  // C == C_{TT-1}
    ab[(size_t)(TT - 1) * CC + j] = a_last;
    if (L == TT) s_last[j] = a_last;
  }
  __syncthreads();

  if (tid < 64) {
    float4 v = ((const float4*)s_last)[lane];
    float m = fmaxf(fmaxf(v.x, v.y), fmaxf(v.z, v.w));
    #pragma unroll
    for (int off = 32; off >= 1; off >>= 1)
      m = fmaxf(m, __shfl_xor(m, off, 64));
    float s = __expf(v.x - m) + __expf(v.y - m) + __expf(v.z - m) + __expf(v.w - m);
    #pragma unroll
    for (int off = 32; off >= 1; off >>= 1)
      s += __shfl_xor(s, off, 64);
    if (lane == 0) out_logz[b] = m + __logf(s);
  }
}

extern "C" void kernel_launch(void* const* d_in, const int* in_sizes, int n_in,
                              void* d_out, int out_size, void* d_ws, size_t ws_size,
                              hipStream_t stream) {
  const float* emis = (const float*)d_in[0];
  const float* trans = (const float*)d_in[1];
  const int* seq_lens = (const int*)d_in[2];
  float* out_alpha = (float*)d_out;
  float* out_logz = out_alpha + (size_t)BB * TT * CC;
  hipLaunchKernelGGL(crf_fwd, dim3(BB), dim3(768), 0, stream,
                     emis, trans, seq_lens, out_alpha, out_logz);
}